// Round 7
// baseline (6226.334 us; speedup 1.0000x reference)
//
#include <hip/hip_runtime.h>
#include <math.h>

typedef _Float16 f16;
typedef _Float16 f16x8 __attribute__((ext_vector_type(8)));
typedef float f32x4 __attribute__((ext_vector_type(4)));
typedef unsigned int u32;
typedef unsigned short u16;

#define M_DIM 4096
#define T_X   128
#define NV    256
#define NA    512
#define NG    2048
#define NKT   24   // gates k-tiles of 32 (8 X-tiles + 16 h-tiles)

__device__ __forceinline__ float sigf(float x) { return 1.0f / (1.0f + __expf(-x)); }
__device__ __forceinline__ float tanh_fast(float x) {
    float t = __expf(2.0f * x);
    return (t - 1.0f) / (t + 1.0f);
}

#define GLOAD_LDS16(G, L) \
    __builtin_amdgcn_global_load_lds((const __attribute__((address_space(1))) u32*)(G), \
                                     (__attribute__((address_space(3))) u32*)(L), 16, 0, 0)

// ============================ prep =============================
__global__ void prep(const float* __restrict__ X,
                     const float* __restrict__ a0, const float* __restrict__ c0,
                     const float* __restrict__ W_ih, const float* __restrict__ W_hh,
                     const float* __restrict__ b_ih, const float* __restrict__ b_hh,
                     const float* __restrict__ W_out,
                     u16* __restrict__ H0, float* __restrict__ cws,
                     u16* __restrict__ BG, u16* __restrict__ BOs, u16* __restrict__ BOo,
                     float* __restrict__ bs, u16* __restrict__ Xf, u32* __restrict__ cnt)
{
    const int N_BG  = NKT * 16 * 4096;   // 1,572,864
    const int N_BOS = 16 * 16 * 512;     // 131,072
    const int N_BOO = 16 * 4 * 2048;     // 131,072
    const int N_BS  = NG;                // 2,048
    const int N_H   = 32 * 16 * 4096;    // 2,097,152
    const int N_XF  = 2 * 32 * 8 * 4096; // 2,097,152 (timesteps 0 and 1)
    const int N_C   = M_DIM * NA;        // 2,097,152
    const int N_CNT = 32 * T_X * 16;     // 65,536 u32 barrier counters
    const int NT = N_BG + N_BOS + N_BOO + N_BS + N_H + N_XF + N_C + N_CNT;
    for (int idx = blockIdx.x * blockDim.x + threadIdx.x; idx < NT;
         idx += gridDim.x * blockDim.x) {
        int i = idx;
        if (i < N_BG) {
            int tile = i >> 12, w = i & 4095;
            int jb = tile & 15, kt = tile >> 4;
            int f = w >> 9, lane = (w >> 3) & 63, e = w & 7;
            int wcc = f >> 2, g = f & 3;
            int n = g * NA + jb * 32 + wcc * 16 + (lane & 15);
            int k = kt * 32 + ((lane >> 4) << 3) + e;
            float v = (k < NV) ? W_ih[n * NV + k] : W_hh[n * NA + (k - NV)];
            BG[i] = __builtin_bit_cast(u16, (f16)v);
            continue;
        }
        i -= N_BG;
        if (i < N_BOS) {
            int tile = i >> 9, w = i & 511;
            int s = tile & 15, kt = tile >> 4;
            int lane = w >> 3, e = w & 7;
            int n = s * 16 + (lane & 15);
            int k = kt * 32 + ((lane >> 4) << 3) + e;
            BOs[i] = __builtin_bit_cast(u16, (f16)W_out[n * NA + k]);
            continue;
        }
        i -= N_BOS;
        if (i < N_BOO) {
            int tile = i >> 11, w = i & 2047;
            int nb = tile & 3, kt = tile >> 2;
            int f = w >> 9, lane = (w >> 3) & 63, e = w & 7;
            int n = nb * 64 + f * 16 + (lane & 15);
            int k = kt * 32 + ((lane >> 4) << 3) + e;
            BOo[i] = __builtin_bit_cast(u16, (f16)W_out[n * NA + k]);
            continue;
        }
        i -= N_BOO;
        if (i < N_BS) { bs[i] = b_ih[i] + b_hh[i]; continue; }
        i -= N_BS;
        if (i < N_H) {
            int tile = i >> 12, w = i & 4095;
            int kt = tile & 15, mb = tile >> 4;
            int mf = w >> 9, lane = (w >> 3) & 63, e = w & 7;
            int m = mb * 128 + mf * 16 + (lane & 15);
            int k = kt * 32 + ((lane >> 4) << 3) + e;
            H0[i] = __builtin_bit_cast(u16, (f16)a0[m * NA + k]);
            continue;
        }
        i -= N_H;
        if (i < N_XF) {
            int b = i >> 20, j = i & 1048575;
            int tile = j >> 12, w = j & 4095;
            int kt = tile & 7, mb = tile >> 3;
            int mf = w >> 9, lane = (w >> 3) & 63, e = w & 7;
            int m = mb * 128 + mf * 16 + (lane & 15);
            int k = kt * 32 + ((lane >> 4) << 3) + e;
            Xf[i] = __builtin_bit_cast(u16, (f16)X[(size_t)m * (T_X * NV) + b * NV + k]);
            continue;
        }
        i -= N_XF;
        if (i < N_C) {
            int id  = i >> 12;
            int rem = i & 4095;
            int tid = rem >> 4, r16 = rem & 15;
            int fm = r16 >> 2, q = r16 & 3;
            int xcd = id & 7, g2 = id >> 3;
            int jb = g2 & 15, mb = xcd + 8 * (g2 >> 4);
            int lane = tid & 63, wv = tid >> 6;
            int wr = wv >> 1, wc = wv & 1;
            int ll = lane & 15, lh = lane >> 4;
            int m = mb * 128 + (wr * 4 + fm) * 16 + lh * 4 + q;
            int col = jb * 32 + wc * 16 + ll;
            cws[i] = c0[(size_t)m * NA + col];
            continue;
        }
        i -= N_C;
        cnt[i] = 0u;
    }
}

// ====================== persistent LSTM kernel ======================
// All 128 steps in one cooperative launch; per-mb 16-block atomic barriers
// (NOT grid.sync). c/bias/BO live in registers the whole time.
// grid 512 (2 blocks/CU), 256 threads = 4 waves (2x2). LDS 64KB = 4 staging bufs.
__global__ __launch_bounds__(256, 2)
void lstm_persist(const float* __restrict__ X,
                  u16* __restrict__ Xf0, u16* __restrict__ Xf1, u16* __restrict__ Xf2,
                  u16* __restrict__ H0, u16* __restrict__ H1, u16* __restrict__ H2,
                  const float* __restrict__ cws,
                  const u16* __restrict__ BG, const u16* __restrict__ BOs,
                  const float* __restrict__ bs, const float* __restrict__ b_out,
                  float* __restrict__ out, u32* __restrict__ cnt)
{
    __shared__ char smem[65536];   // 4 x 16 KB staging buffers

    const int id  = blockIdx.x;
    const int xcd = id & 7, g2 = id >> 3;
    const int jb  = g2 & 15;
    const int mb  = xcd + 8 * (g2 >> 4);   // 16 jb-blocks of an mb share an XCD

    const int tid = threadIdx.x, lane = tid & 63, wv = tid >> 6;
    const int wr = wv >> 1, wc = wv & 1;
    const int ll = lane & 15, lh = lane >> 4;
    const int colg = jb * 32 + wc * 16 + ll;

    // ---- one-time register state (lives across all 128 steps) ----
    f16x8 bo_w[8];   // out-proj strips for this wave: strip s = 2*i + wc
    #pragma unroll
    for (int i = 0; i < 8; ++i) {
        int s = i * 2 + wc;
        bo_w[i] = *(const f16x8*)(BOs + ((size_t)(s * 16 + jb)) * 512 + lane * 8);
    }
    float bsv[4];
    #pragma unroll
    for (int g = 0; g < 4; ++g) bsv[g] = bs[g * NA + colg];
    float bo_r = b_out[jb * 16 + ll];
    f32x4 cv4[4];
    {
        const f32x4* cb = (const f32x4*)(cws + ((size_t)id * 256 + tid) * 16);
        #pragma unroll
        for (int i = 0; i < 4; ++i) cv4[i] = cb[i];
    }
    asm volatile("s_waitcnt vmcnt(0)" ::: "memory");
    __syncthreads();

    const u16* Hin; u16* Hout; const u16* Xc; u16* Xn;

    auto stage = [&](int ktn, int buf) {
        char* base = smem + buf * 16384;
        const char* asrc = (ktn < 8)
            ? (const char*)(Xc + ((size_t)(mb * 8 + ktn)) * 4096)
            : (const char*)(Hin + ((size_t)(mb * 16 + (ktn - 8))) * 4096);
        GLOAD_LDS16(asrc + wv * 2048 + lane * 16,        base + wv * 2048);
        GLOAD_LDS16(asrc + wv * 2048 + 1024 + lane * 16, base + wv * 2048 + 1024);
        const char* bsrc = (const char*)(BG + ((size_t)(ktn * 16 + jb)) * 4096);
        GLOAD_LDS16(bsrc + wv * 2048 + lane * 16,        base + 8192 + wv * 2048);
        GLOAD_LDS16(bsrc + wv * 2048 + 1024 + lane * 16, base + 8192 + wv * 2048 + 1024);
    };
    auto stageA = [&](int ktn, int buf) {   // h-tile only (final out pass)
        char* base = smem + buf * 16384;
        const char* asrc = (const char*)(Hin + ((size_t)(mb * 16 + ktn)) * 4096);
        GLOAD_LDS16(asrc + wv * 2048 + lane * 16,        base + wv * 2048);
        GLOAD_LDS16(asrc + wv * 2048 + 1024 + lane * 16, base + wv * 2048 + 1024);
    };

    f32x4 acc[4][4];
    f32x4 acc_o[4];

    auto compute = [&](int ktn, int buf, int do_out) {
        const char* base = smem + buf * 16384;
        f16x8 af[4], bfr[4];
        #pragma unroll
        for (int g = 0; g < 4; ++g)
            bfr[g] = *(const f16x8*)(base + 8192 + (((wc * 4 + g) * 64 + lane) << 4));
        #pragma unroll
        for (int fm = 0; fm < 4; ++fm)
            af[fm] = *(const f16x8*)(base + (((wr * 4 + fm) * 64 + lane) << 4));
        #pragma unroll
        for (int fm = 0; fm < 4; ++fm)
            #pragma unroll
            for (int g = 0; g < 4; ++g)
                acc[fm][g] = __builtin_amdgcn_mfma_f32_16x16x32_f16(af[fm], bfr[g], acc[fm][g], 0, 0, 0);
        if (do_out && ktn >= 8 && ((ktn - 8) & 1) == wc) {
            f16x8 bo = bo_w[(ktn - 8) >> 1];   // static index after unroll
            #pragma unroll
            for (int fm = 0; fm < 4; ++fm)
                acc_o[fm] = __builtin_amdgcn_mfma_f32_16x16x32_f16(af[fm], bo, acc_o[fm], 0, 0, 0);
        }
    };
    auto computeO = [&](int ktn, int buf) {   // final out pass
        const char* base = smem + buf * 16384;
        if ((ktn & 1) == wc) {
            f16x8 bo = bo_w[ktn >> 1];
            #pragma unroll
            for (int fm = 0; fm < 4; ++fm) {
                f16x8 af = *(const f16x8*)(base + (((wr * 4 + fm) * 64 + lane) << 4));
                acc_o[fm] = __builtin_amdgcn_mfma_f32_16x16x32_f16(af, bo, acc_o[fm], 0, 0, 0);
            }
        }
    };
    auto reduce_out = [&](float* out_t) {
        if (wc == 1) {
            float* P = (float*)(smem + wr * 4096);
            #pragma unroll
            for (int fm = 0; fm < 4; ++fm)
                #pragma unroll
                for (int q = 0; q < 4; ++q)
                    P[(fm * 16 + lh * 4 + q) * 16 + ll] = acc_o[fm][q];
        }
        __syncthreads();
        if (wc == 0) {
            const float* P = (const float*)(smem + wr * 4096);
            #pragma unroll
            for (int fm = 0; fm < 4; ++fm)
                #pragma unroll
                for (int q = 0; q < 4; ++q) {
                    const int rloc = wr * 64 + fm * 16 + lh * 4 + q;
                    float v = acc_o[fm][q] + P[(fm * 16 + lh * 4 + q) * 16 + ll] + bo_r;
                    __builtin_nontemporal_store(
                        v, out_t + ((size_t)mb * 128 + rloc) * NV + jb * 16 + ll);
                }
        }
    };

    #pragma unroll 1
    for (int t = 0; t < T_X; ++t) {
        const int r3 = t % 3;
        Hin  = (r3 == 0) ? H0 : (r3 == 1) ? H1 : H2;
        Hout = (r3 == 0) ? H1 : (r3 == 1) ? H2 : H0;
        Xc   = (r3 == 0) ? Xf0 : (r3 == 1) ? Xf1 : Xf2;
        Xn   = (r3 == 0) ? Xf2 : (r3 == 1) ? Xf0 : Xf1;
        const int do_out = (t > 0);

        #pragma unroll
        for (int a = 0; a < 4; ++a) {
            acc_o[a] = (f32x4){0.f, 0.f, 0.f, 0.f};
            #pragma unroll
            for (int b = 0; b < 4; ++b) acc[a][b] = (f32x4){0.f, 0.f, 0.f, 0.f};
        }

        // ---- 4-deep pipelined k-loop (fully unrolled; counted vmcnt) ----
        stage(0, 0); stage(1, 1); stage(2, 2);
        #pragma unroll
        for (int kt = 0; kt < NKT; ++kt) {
            if (kt <= NKT - 3)      asm volatile("s_waitcnt vmcnt(8)" ::: "memory");
            else if (kt == NKT - 2) asm volatile("s_waitcnt vmcnt(4)" ::: "memory");
            else                    asm volatile("s_waitcnt vmcnt(0)" ::: "memory");
            __builtin_amdgcn_s_barrier();
            if (kt + 3 < NKT) stage(kt + 3, (kt + 3) & 3);
            compute(kt, kt & 3, do_out);
        }

        // ---- epilogue A: activations + cell update (c in regs) + h store ----
        u16* htile = Hout + ((size_t)(mb * 16 + jb)) * 4096;
        const int ksub = wc * 2 + (ll >> 3);
        const int e = ll & 7;
        #pragma unroll
        for (int fm = 0; fm < 4; ++fm) {
            const int mf = wr * 4 + fm;
            #pragma unroll
            for (int q = 0; q < 4; ++q) {
                float gi = acc[fm][0][q] + bsv[0];
                float gf = acc[fm][1][q] + bsv[1];
                float gg = acc[fm][2][q] + bsv[2];
                float go = acc[fm][3][q] + bsv[3];
                float iv = sigf(gi), fv = sigf(gf);
                float gv = tanh_fast(gg), ov = sigf(go);
                float cn = fv * cv4[fm][q] + iv * gv;
                float hn = ov * tanh_fast(cn);
                cv4[fm][q] = cn;
                const int lanep = (lh * 4 + q) + 16 * ksub;
                htile[(mf * 64 + lanep) * 8 + e] = __builtin_bit_cast(u16, (f16)hn);
            }
        }

        // ---- epilogue B: out[t-1] cross-wave reduce ----
        if (do_out) reduce_out(out + (size_t)(t - 1) * M_DIM * NV);

        // ---- epilogue C: convert X[:, t+2] -> fragment-linear fp16 ----
        if (t < T_X - 2 && jb < 8) {
            const int r = tid >> 1, kh = tid & 1;
            const float* xsrc = X + ((size_t)(mb * 128 + r) * T_X + (t + 2)) * NV + jb * 32 + kh * 16;
            f32x4 xv[4];
            #pragma unroll
            for (int i = 0; i < 4; ++i)
                xv[i] = __builtin_nontemporal_load((const f32x4*)(xsrc + i * 4));
            u16* xt = Xn + ((size_t)(mb * 8 + jb)) * 4096;
            const int mf = r >> 4;
            #pragma unroll
            for (int s = 0; s < 2; ++s) {
                f16x8 v;
                #pragma unroll
                for (int j = 0; j < 8; ++j) v[j] = (f16)xv[s * 2 + (j >> 2)][j & 3];
                const int lanep = (r & 15) + 16 * (kh * 2 + s);
                *(f16x8*)(xt + (mf * 64 + lanep) * 8) = v;
            }
        }

        // ---- per-mb 16-block barrier (release/acquire, agent scope) ----
        asm volatile("s_waitcnt vmcnt(0)" ::: "memory");
        __syncthreads();
        if (tid == 0) {
            u32* ctr = cnt + (((size_t)t * 32) + mb) * 16;
            __hip_atomic_fetch_add(ctr, 1u, __ATOMIC_RELEASE, __HIP_MEMORY_SCOPE_AGENT);
            while (__hip_atomic_load(ctr, __ATOMIC_RELAXED, __HIP_MEMORY_SCOPE_AGENT) < 16u)
                __builtin_amdgcn_s_sleep(1);
            (void)__hip_atomic_load(ctr, __ATOMIC_ACQUIRE, __HIP_MEMORY_SCOPE_AGENT);
        }
        __syncthreads();
    }

    // ---- final pass: out[127] = h_128 @ W_out^T + b_out (h_128 in H2: 128%3==2) ----
    Hin = H2;
    #pragma unroll
    for (int a = 0; a < 4; ++a) acc_o[a] = (f32x4){0.f, 0.f, 0.f, 0.f};
    stageA(0, 0); stageA(1, 1); stageA(2, 2);
    #pragma unroll
    for (int kt = 0; kt < 16; ++kt) {
        if (kt <= 13)      asm volatile("s_waitcnt vmcnt(4)" ::: "memory");
        else if (kt == 14) asm volatile("s_waitcnt vmcnt(2)" ::: "memory");
        else               asm volatile("s_waitcnt vmcnt(0)" ::: "memory");
        __builtin_amdgcn_s_barrier();
        if (kt + 3 < 16) stageA(kt + 3, (kt + 3) & 3);
        computeO(kt, kt & 3);
    }
    reduce_out(out + (size_t)(T_X - 1) * M_DIM * NV);
}

// ====================== fallback (multi-launch) kernels ======================
__global__ __launch_bounds__(256, 2)
void step_fused(const float* __restrict__ X,
                const u16* __restrict__ Xf_cur, u16* __restrict__ Xf_n2,
                const u16* __restrict__ Hin, u16* __restrict__ Hout,
                float* __restrict__ cws,
                const u16* __restrict__ BG, const u16* __restrict__ BOs,
                const float* __restrict__ bs, const float* __restrict__ b_out,
                float* __restrict__ out_prev, int t, int do_out, int do_xconv)
{
    __shared__ char smem[65536];
    char* BO_lds = smem + 49152;

    const int id  = blockIdx.x;
    const int xcd = id & 7, g2 = id >> 3;
    const int jb  = g2 & 15;
    const int mb  = xcd + 8 * (g2 >> 4);

    const int tid = threadIdx.x, lane = tid & 63, wv = tid >> 6;
    const int wr = wv >> 1, wc = wv & 1;

    f32x4 cv4[4];
    {
        const f32x4* cb = (const f32x4*)(cws + ((size_t)id * 256 + tid) * 16);
        #pragma unroll
        for (int i = 0; i < 4; ++i) cv4[i] = cb[i];
    }

    f32x4 acc[4][4];
    #pragma unroll
    for (int a = 0; a < 4; ++a)
        #pragma unroll
        for (int b = 0; b < 4; ++b) acc[a][b] = (f32x4){0.f, 0.f, 0.f, 0.f};
    f32x4 acc_o[4];
    #pragma unroll
    for (int a = 0; a < 4; ++a) acc_o[a] = (f32x4){0.f, 0.f, 0.f, 0.f};

    auto stage = [&](int ktn, int buf) {
        char* base = smem + buf * 16384;
        const char* asrc = (ktn < 8)
            ? (const char*)(Xf_cur + ((size_t)(mb * 8 + ktn)) * 4096)
            : (const char*)(Hin + ((size_t)(mb * 16 + (ktn - 8))) * 4096);
        GLOAD_LDS16(asrc + wv * 2048 + lane * 16,        base + wv * 2048);
        GLOAD_LDS16(asrc + wv * 2048 + 1024 + lane * 16, base + wv * 2048 + 1024);
        const char* bsrc = (const char*)(BG + ((size_t)(ktn * 16 + jb)) * 4096);
        GLOAD_LDS16(bsrc + wv * 2048 + lane * 16,        base + 8192 + wv * 2048);
        GLOAD_LDS16(bsrc + wv * 2048 + 1024 + lane * 16, base + 8192 + wv * 2048 + 1024);
    };
    auto compute = [&](int ktn, int buf) {
        const char* base = smem + buf * 16384;
        f16x8 af[4], bfr[4];
        #pragma unroll
        for (int g = 0; g < 4; ++g)
            bfr[g] = *(const f16x8*)(base + 8192 + (((wc * 4 + g) * 64 + lane) << 4));
        #pragma unroll
        for (int fm = 0; fm < 4; ++fm)
            af[fm] = *(const f16x8*)(base + (((wr * 4 + fm) * 64 + lane) << 4));
        #pragma unroll
        for (int fm = 0; fm < 4; ++fm)
            #pragma unroll
            for (int g = 0; g < 4; ++g)
                acc[fm][g] = __builtin_amdgcn_mfma_f32_16x16x32_f16(af[fm], bfr[g], acc[fm][g], 0, 0, 0);
        if (do_out && ktn >= 8 && ((ktn - 8) & 1) == wc) {
            f16x8 bo = *(const f16x8*)(BO_lds + (ktn - 8) * 1024 + lane * 16);
            #pragma unroll
            for (int fm = 0; fm < 4; ++fm)
                acc_o[fm] = __builtin_amdgcn_mfma_f32_16x16x32_f16(af[fm], bo, acc_o[fm], 0, 0, 0);
        }
    };

    #pragma unroll
    for (int i = 0; i < 4; ++i) {
        int kt = wv * 4 + i;
        const char* src = (const char*)(BOs + ((size_t)(kt * 16 + jb)) * 512);
        GLOAD_LDS16(src + lane * 16, BO_lds + kt * 1024);
    }
    stage(0, 0);
    stage(1, 1);

    int cur = 0;
    for (int kt = 0; kt < NKT - 1; ++kt) {
        asm volatile("s_waitcnt vmcnt(4)" ::: "memory");
        __builtin_amdgcn_s_barrier();
        if (kt + 2 < NKT) {
            int stb = cur + 2; if (stb >= 3) stb -= 3;
            stage(kt + 2, stb);
        }
        compute(kt, cur);
        ++cur; if (cur == 3) cur = 0;
    }
    asm volatile("s_waitcnt vmcnt(0)" ::: "memory");
    __builtin_amdgcn_s_barrier();
    compute(NKT - 1, cur);

    const int ll = lane & 15, lh = lane >> 4;
    u16* htile = Hout + ((size_t)(mb * 16 + jb)) * 4096;
    const int ksub = wc * 2 + (ll >> 3);
    const int e = ll & 7;
    const int colg = jb * 32 + wc * 16 + ll;
    float bsv[4];
    #pragma unroll
    for (int g = 0; g < 4; ++g) bsv[g] = bs[g * NA + colg];

    #pragma unroll
    for (int fm = 0; fm < 4; ++fm) {
        const int mf = wr * 4 + fm;
        #pragma unroll
        for (int q = 0; q < 4; ++q) {
            float gi = acc[fm][0][q] + bsv[0];
            float gf = acc[fm][1][q] + bsv[1];
            float gg = acc[fm][2][q] + bsv[2];
            float go = acc[fm][3][q] + bsv[3];
            float iv = sigf(gi), fv = sigf(gf);
            float gv = tanh_fast(gg), ov = sigf(go);
            float cn = fv * cv4[fm][q] + iv * gv;
            float hn = ov * tanh_fast(cn);
            cv4[fm][q] = cn;
            const int lanep = (lh * 4 + q) + 16 * ksub;
            htile[(mf * 64 + lanep) * 8 + e] = __builtin_bit_cast(u16, (f16)hn);
        }
    }
    {
        f32x4* cb = (f32x4*)(cws + ((size_t)id * 256 + tid) * 16);
        #pragma unroll
        for (int i = 0; i < 4; ++i) cb[i] = cv4[i];
    }

    if (do_out) {
        if (wc == 1) {
            float* P = (float*)(smem + wr * 4096);
            #pragma unroll
            for (int fm = 0; fm < 4; ++fm)
                #pragma unroll
                for (int q = 0; q < 4; ++q)
                    P[(fm * 16 + lh * 4 + q) * 16 + ll] = acc_o[fm][q];
        }
        __syncthreads();
        if (wc == 0) {
            const float* P = (const float*)(smem + wr * 4096);
            const float bo = b_out[jb * 16 + ll];
            #pragma unroll
            for (int fm = 0; fm < 4; ++fm)
                #pragma unroll
                for (int q = 0; q < 4; ++q) {
                    const int rloc = wr * 64 + fm * 16 + lh * 4 + q;
                    float v = acc_o[fm][q] + P[(fm * 16 + lh * 4 + q) * 16 + ll] + bo;
                    __builtin_nontemporal_store(
                        v, out_prev + ((size_t)mb * 128 + rloc) * NV + jb * 16 + ll);
                }
        }
    }

    if (do_xconv && jb < 8) {
        const int r = tid >> 1, kh = tid & 1;
        const float* xsrc = X + ((size_t)(mb * 128 + r) * T_X + (t + 2)) * NV + jb * 32 + kh * 16;
        f32x4 xv[4];
        #pragma unroll
        for (int i = 0; i < 4; ++i)
            xv[i] = __builtin_nontemporal_load((const f32x4*)(xsrc + i * 4));
        u16* xt = Xf_n2 + ((size_t)(mb * 8 + jb)) * 4096;
        const int mf = r >> 4;
        #pragma unroll
        for (int s = 0; s < 2; ++s) {
            f16x8 v;
            #pragma unroll
            for (int j = 0; j < 8; ++j) v[j] = (f16)xv[s * 2 + (j >> 2)][j & 3];
            const int lanep = (r & 15) + 16 * (kh * 2 + s);
            *(f16x8*)(xt + (mf * 64 + lanep) * 8) = v;
        }
    }
}

__global__ __launch_bounds__(256)
void out_proj(const u16* __restrict__ Hin, const u16* __restrict__ BO,
              const float* __restrict__ b_out, float* __restrict__ out)
{
    __shared__ char smem[24576];

    const int id  = blockIdx.x;
    const int xcd = id & 7, g2 = id >> 3;
    const int nb  = g2 & 3;
    const int mb  = xcd + 8 * (g2 >> 2);

    const int tid = threadIdx.x, lane = tid & 63, wv = tid >> 6;
    const int wr = wv >> 1, wc = wv & 1;

    f32x4 acc[4][2];
    #pragma unroll
    for (int a = 0; a < 4; ++a) { acc[a][0] = (f32x4){0,0,0,0}; acc[a][1] = (f32x4){0,0,0,0}; }

    auto stage = [&](int kt, int buf) {
        char* base = smem + buf * 12288;
        const char* asrc = (const char*)(Hin + ((size_t)(mb * 16 + kt)) * 4096);
        GLOAD_LDS16(asrc + wv * 2048 + lane * 16,        base + wv * 2048);
        GLOAD_LDS16(asrc + wv * 2048 + 1024 + lane * 16, base + wv * 2048 + 1024);
        const char* bsrc = (const char*)(BO + ((size_t)(kt * 4 + nb)) * 2048);
        GLOAD_LDS16(bsrc + wv * 1024 + lane * 16, base + 8192 + wv * 1024);
    };
    auto compute = [&](int buf) {
        const char* base = smem + buf * 12288;
        f16x8 bfr[2];
        #pragma unroll
        for (int fq = 0; fq < 2; ++fq)
            bfr[fq] = *(const f16x8*)(base + 8192 + (((wc * 2 + fq) * 64 + lane) << 4));
        #pragma unroll
        for (int fm = 0; fm < 4; ++fm) {
            f16x8 af = *(const f16x8*)(base + (((wr * 4 + fm) * 64 + lane) << 4));
            #pragma unroll
            for (int fq = 0; fq < 2; ++fq)
                acc[fm][fq] = __builtin_amdgcn_mfma_f32_16x16x32_f16(af, bfr[fq], acc[fm][fq], 0, 0, 0);
        }
    };

    stage(0, 0);
    __syncthreads();
    for (int kt = 0; kt < 16; ++kt) {
        const int cur = kt & 1;
        if (kt + 1 < 16) stage(kt + 1, cur ^ 1);
        compute(cur);
        __syncthreads();
    }

    const int ll = lane & 15, lh = lane >> 4;
    float bov[2];
    #pragma unroll
    for (int fq = 0; fq < 2; ++fq) bov[fq] = b_out[nb * 64 + (wc * 2 + fq) * 16 + ll];

    #pragma unroll
    for (int fm = 0; fm < 4; ++fm)
        #pragma unroll
        for (int fq = 0; fq < 2; ++fq)
            #pragma unroll
            for (int q = 0; q < 4; ++q) {
                const int row = mb * 128 + wr * 64 + fm * 16 + lh * 4 + q;
                const int col = nb * 64 + (wc * 2 + fq) * 16 + ll;
                __builtin_nontemporal_store(acc[fm][fq][q] + bov[fq],
                                            out + (size_t)row * NV + col);
            }
}

// ============================ host =============================
extern "C" void kernel_launch(void* const* d_in, const int* in_sizes, int n_in,
                              void* d_out, int out_size, void* d_ws, size_t ws_size,
                              hipStream_t stream) {
    const float* X     = (const float*)d_in[0];
    const float* a0    = (const float*)d_in[1];
    const float* c0    = (const float*)d_in[2];
    const float* W_ih  = (const float*)d_in[3];
    const float* W_hh  = (const float*)d_in[4];
    const float* b_ih  = (const float*)d_in[5];
    const float* b_hh  = (const float*)d_in[6];
    const float* W_out = (const float*)d_in[7];
    const float* b_out = (const float*)d_in[8];
    float* out = (float*)d_out;

    char* w = (char*)d_ws;
    u16*   H0   = (u16*)(w);                                   // 4 MB
    u16*   H1   = (u16*)(w + ((size_t)4 << 20));               // 4 MB
    u16*   H2   = (u16*)(w + ((size_t)8 << 20));               // 4 MB
    float* cws  = (float*)(w + ((size_t)12 << 20));            // 8 MB
    u16*   BG   = (u16*)(w + ((size_t)20 << 20));              // 3 MB
    u16*   BOs  = (u16*)(w + ((size_t)23 << 20));              // 256 KB
    u16*   BOo  = (u16*)(w + ((size_t)23 << 20) + 262144);     // 256 KB
    float* bsv  = (float*)(w + ((size_t)23 << 20) + 524288);   // 8 KB
    u16*   Xf0  = (u16*)(w + ((size_t)24 << 20));              // 2 MB
    u16*   Xf1  = (u16*)(w + ((size_t)26 << 20));              // 2 MB
    u16*   Xf2  = (u16*)(w + ((size_t)28 << 20));              // 2 MB
    u32*   cnt  = (u32*)(w + ((size_t)30 << 20));              // 256 KB

    prep<<<8192, 256, 0, stream>>>(X, a0, c0, W_ih, W_hh, b_ih, b_hh, W_out,
                                   H0, cws, BG, BOs, BOo, bsv, Xf0, cnt);

    void* args[] = {(void*)&X, (void*)&Xf0, (void*)&Xf1, (void*)&Xf2,
                    (void*)&H0, (void*)&H1, (void*)&H2,
                    (void*)&cws, (void*)&BG, (void*)&BOs, (void*)&bsv, (void*)&b_out,
                    (void*)&out, (void*)&cnt};
    hipError_t err = hipLaunchCooperativeKernel((const void*)lstm_persist,
                                                dim3(512), dim3(256), args, 0, stream);
    if (err != hipSuccess) {
        // fallback: per-step launches (round-3 structure, c via cws normal loads)
        for (int t = 0; t < T_X; ++t) {
            const u16* hi = (t & 1) ? H1 : H0;
            u16*       ho = (t & 1) ? H0 : H1;
            const u16* xc = (t % 3 == 0) ? Xf0 : (t % 3 == 1) ? Xf1 : Xf2;
            u16*       xn = (t % 3 == 0) ? Xf2 : (t % 3 == 1) ? Xf0 : Xf1;
            float* outp = out + (size_t)(t > 0 ? t - 1 : 0) * M_DIM * NV;
            step_fused<<<512, 256, 0, stream>>>(X, xc, xn, hi, ho, cws, BG, BOs, bsv, b_out,
                                                outp, t, t > 0 ? 1 : 0, t < T_X - 2 ? 1 : 0);
        }
        out_proj<<<128, 256, 0, stream>>>(H0, BOo, b_out, out + (size_t)(T_X - 1) * M_DIM * NV);
    }
}

// Round 8
// 3447.817 us; speedup vs baseline: 1.8059x; 1.8059x over previous
//
#include <hip/hip_runtime.h>
#include <math.h>

typedef _Float16 f16;
typedef _Float16 f16x8 __attribute__((ext_vector_type(8)));
typedef float f32x4 __attribute__((ext_vector_type(4)));
typedef unsigned int u32;
typedef unsigned short u16;

#define M_DIM 4096
#define T_X   128
#define NV    256
#define NA    512
#define NG    2048
#define NKT   24   // gates k-tiles of 32 (8 X-tiles + 16 h-tiles)

__device__ __forceinline__ float sigf(float x) { return 1.0f / (1.0f + __expf(-x)); }
__device__ __forceinline__ float tanh_fast(float x) {
    float t = __expf(2.0f * x);
    return (t - 1.0f) / (t + 1.0f);
}

#define GLOAD_LDS16(G, L) \
    __builtin_amdgcn_global_load_lds((const __attribute__((address_space(1))) u32*)(G), \
                                     (__attribute__((address_space(3))) u32*)(L), 16, 0, 0)

// ============================ prep =============================
// BG : [kt 24][jb 16] tiles 4096 u16 (gates weights, fragment-linear)
// BOs: [kt 16][s 16] strips 512 u16 (fused out-proj weights)
// BOo: [kt 16][nb 4] tiles 2048 u16 (final out_proj kernel)
// H  : [mb 32][kt 16] tiles 4096 u16 fragment-linear h (128 rows x 32 k)
// Xf : 3 rotating buffers of [mb 32][kt 8] tiles 4096 u16; prep fills t=0, t=1
// cws: fragment-contiguous c for 512-thread blocks: [(id*512 + tid)*8 + fm*4 + q]
__global__ void prep(const float* __restrict__ X,
                     const float* __restrict__ a0, const float* __restrict__ c0,
                     const float* __restrict__ W_ih, const float* __restrict__ W_hh,
                     const float* __restrict__ b_ih, const float* __restrict__ b_hh,
                     const float* __restrict__ W_out,
                     u16* __restrict__ H0, float* __restrict__ cws,
                     u16* __restrict__ BG, u16* __restrict__ BOs, u16* __restrict__ BOo,
                     float* __restrict__ bs, u16* __restrict__ Xf)
{
    const int N_BG  = NKT * 16 * 4096;   // 1,572,864
    const int N_BOS = 16 * 16 * 512;     // 131,072
    const int N_BOO = 16 * 4 * 2048;     // 131,072
    const int N_BS  = NG;                // 2,048
    const int N_H   = 32 * 16 * 4096;    // 2,097,152
    const int N_XF  = 2 * 32 * 8 * 4096; // 2,097,152 (timesteps 0 and 1)
    const int N_C   = M_DIM * NA;        // 2,097,152
    const int NT = N_BG + N_BOS + N_BOO + N_BS + N_H + N_XF + N_C;
    for (int idx = blockIdx.x * blockDim.x + threadIdx.x; idx < NT;
         idx += gridDim.x * blockDim.x) {
        int i = idx;
        if (i < N_BG) {
            int tile = i >> 12, w = i & 4095;
            int jb = tile & 15, kt = tile >> 4;
            int f = w >> 9, lane = (w >> 3) & 63, e = w & 7;
            int wcc = f >> 2, g = f & 3;
            int n = g * NA + jb * 32 + wcc * 16 + (lane & 15);
            int k = kt * 32 + ((lane >> 4) << 3) + e;
            float v = (k < NV) ? W_ih[n * NV + k] : W_hh[n * NA + (k - NV)];
            BG[i] = __builtin_bit_cast(u16, (f16)v);
            continue;
        }
        i -= N_BG;
        if (i < N_BOS) {
            int tile = i >> 9, w = i & 511;
            int s = tile & 15, kt = tile >> 4;
            int lane = w >> 3, e = w & 7;
            int n = s * 16 + (lane & 15);
            int k = kt * 32 + ((lane >> 4) << 3) + e;
            BOs[i] = __builtin_bit_cast(u16, (f16)W_out[n * NA + k]);
            continue;
        }
        i -= N_BOS;
        if (i < N_BOO) {
            int tile = i >> 11, w = i & 2047;
            int nb = tile & 3, kt = tile >> 2;
            int f = w >> 9, lane = (w >> 3) & 63, e = w & 7;
            int n = nb * 64 + f * 16 + (lane & 15);
            int k = kt * 32 + ((lane >> 4) << 3) + e;
            BOo[i] = __builtin_bit_cast(u16, (f16)W_out[n * NA + k]);
            continue;
        }
        i -= N_BOO;
        if (i < N_BS) { bs[i] = b_ih[i] + b_hh[i]; continue; }
        i -= N_BS;
        if (i < N_H) {
            int tile = i >> 12, w = i & 4095;
            int kt = tile & 15, mb = tile >> 4;
            int mf = w >> 9, lane = (w >> 3) & 63, e = w & 7;
            int m = mb * 128 + mf * 16 + (lane & 15);
            int k = kt * 32 + ((lane >> 4) << 3) + e;
            H0[i] = __builtin_bit_cast(u16, (f16)a0[m * NA + k]);
            continue;
        }
        i -= N_H;
        if (i < N_XF) {
            int b = i >> 20, j = i & 1048575;
            int tile = j >> 12, w = j & 4095;
            int kt = tile & 7, mb = tile >> 3;
            int mf = w >> 9, lane = (w >> 3) & 63, e = w & 7;
            int m = mb * 128 + mf * 16 + (lane & 15);
            int k = kt * 32 + ((lane >> 4) << 3) + e;
            Xf[i] = __builtin_bit_cast(u16, (f16)X[(size_t)m * (T_X * NV) + b * NV + k]);
            continue;
        }
        i -= N_XF;
        {
            // c init for 512-thread step blocks: i = (id*512 + tid)*8 + fm*4 + q
            int id  = i >> 12;           // block 0..511
            int rem = i & 4095;          // 512 threads x 8
            int tid = rem >> 3, r8 = rem & 7;
            int fm = r8 >> 2, q = r8 & 3;
            int xcd = id & 7, g2 = id >> 3;
            int jb = g2 & 15, mb = xcd + 8 * (g2 >> 4);
            int lane = tid & 63, wv = tid >> 6;     // wv 0..7
            int wr = wv >> 1, wc = wv & 1;          // wr 0..3
            int ll = lane & 15, lh = lane >> 4;
            int m = mb * 128 + (wr * 2 + fm) * 16 + lh * 4 + q;
            int col = jb * 32 + wc * 16 + ll;
            cws[i] = c0[(size_t)m * NA + col];
        }
    }
}

// ====================== fused step kernel (8 waves) ======================
// gates_t + cell update + h_t ; out_{t-1} fused ; X[:, t+2] convert.
// grid 512 (XCD-swizzled), 512 threads = 8 waves (4 wr x 2 wc).
// LDS 64KB: 3 x 16KB staging bufs + 16KB BO strips. 2 blocks/CU = 4 waves/SIMD.
__global__ __launch_bounds__(512, 4)
void step_fused(const float* __restrict__ X,
                const u16* __restrict__ Xf_cur, u16* __restrict__ Xf_n2,
                const u16* __restrict__ Hin, u16* __restrict__ Hout,
                float* __restrict__ cws,
                const u16* __restrict__ BG, const u16* __restrict__ BOs,
                const float* __restrict__ bs, const float* __restrict__ b_out,
                float* __restrict__ out_prev, int t, int do_out, int do_xconv)
{
    __shared__ char smem[65536];
    char* BO_lds = smem + 49152;

    const int id  = blockIdx.x;
    const int xcd = id & 7, g2 = id >> 3;
    const int jb  = g2 & 15;
    const int mb  = xcd + 8 * (g2 >> 4);

    const int tid = threadIdx.x, lane = tid & 63, wv = tid >> 6;  // wv 0..7
    const int wr = wv >> 1, wc = wv & 1;                          // wr 0..3

    f32x4 acc[2][4];
    #pragma unroll
    for (int a = 0; a < 2; ++a)
        #pragma unroll
        for (int b = 0; b < 4; ++b) acc[a][b] = (f32x4){0.f, 0.f, 0.f, 0.f};
    f32x4 acc_o[2];
    acc_o[0] = (f32x4){0.f, 0.f, 0.f, 0.f};
    acc_o[1] = (f32x4){0.f, 0.f, 0.f, 0.f};

    auto stage = [&](int ktn, int buf) {
        char* base = smem + buf * 16384;
        const char* asrc = (ktn < 8)
            ? (const char*)(Xf_cur + ((size_t)(mb * 8 + ktn)) * 4096)
            : (const char*)(Hin + ((size_t)(mb * 16 + (ktn - 8))) * 4096);
        GLOAD_LDS16(asrc + wv * 1024 + lane * 16, base + wv * 1024);
        const char* bsrc = (const char*)(BG + ((size_t)(ktn * 16 + jb)) * 4096);
        GLOAD_LDS16(bsrc + wv * 1024 + lane * 16, base + 8192 + wv * 1024);
    };
    auto compute = [&](int ktn, int buf) {
        const char* base = smem + buf * 16384;
        f16x8 af[2], bfr[4];
        #pragma unroll
        for (int g = 0; g < 4; ++g)
            bfr[g] = *(const f16x8*)(base + 8192 + (((wc * 4 + g) * 64 + lane) << 4));
        #pragma unroll
        for (int fm = 0; fm < 2; ++fm)
            af[fm] = *(const f16x8*)(base + (((wr * 2 + fm) * 64 + lane) << 4));
        #pragma unroll
        for (int fm = 0; fm < 2; ++fm)
            #pragma unroll
            for (int g = 0; g < 4; ++g)
                acc[fm][g] = __builtin_amdgcn_mfma_f32_16x16x32_f16(af[fm], bfr[g], acc[fm][g], 0, 0, 0);
        if (do_out && ktn >= 8 && ((ktn - 8) & 1) == wc) {
            f16x8 bo = *(const f16x8*)(BO_lds + (ktn - 8) * 1024 + lane * 16);
            #pragma unroll
            for (int fm = 0; fm < 2; ++fm)
                acc_o[fm] = __builtin_amdgcn_mfma_f32_16x16x32_f16(af[fm], bo, acc_o[fm], 0, 0, 0);
        }
    };

    // prologue: BO strips (2 loads/wave) + first two pipeline stages (2 loads/wave each)
    #pragma unroll
    for (int i = 0; i < 2; ++i) {
        int kt = wv * 2 + i;
        const char* src = (const char*)(BOs + ((size_t)(kt * 16 + jb)) * 512);
        GLOAD_LDS16(src + lane * 16, BO_lds + kt * 1024);
    }
    stage(0, 0);
    stage(1, 1);

    // main loop: one barrier + counted vmcnt per tile; loads span barriers
    int cur = 0;
    for (int kt = 0; kt < NKT - 1; ++kt) {
        asm volatile("s_waitcnt vmcnt(2)" ::: "memory");
        __builtin_amdgcn_s_barrier();
        if (kt + 2 < NKT) {
            int stb = cur + 2; if (stb >= 3) stb -= 3;
            stage(kt + 2, stb);
        }
        compute(kt, cur);
        ++cur; if (cur == 3) cur = 0;
    }
    asm volatile("s_waitcnt vmcnt(0)" ::: "memory");
    __builtin_amdgcn_s_barrier();
    compute(NKT - 1, cur);

    // ---- epilogue A: bias + activations + cell update + h store ----
    const int ll = lane & 15, lh = lane >> 4;
    const int colg = jb * 32 + wc * 16 + ll;
    float bsv[4];
    #pragma unroll
    for (int g = 0; g < 4; ++g) bsv[g] = bs[g * NA + colg];
    f32x4 cv4[2];
    {
        const f32x4* cb = (const f32x4*)(cws + ((size_t)id * 512 + tid) * 8);
        cv4[0] = cb[0]; cv4[1] = cb[1];
    }

    u16* htile = Hout + ((size_t)(mb * 16 + jb)) * 4096;
    const int ksub = wc * 2 + (ll >> 3);
    const int e = ll & 7;

    #pragma unroll
    for (int fm = 0; fm < 2; ++fm) {
        const int mf = wr * 2 + fm;
        #pragma unroll
        for (int q = 0; q < 4; ++q) {
            float gi = acc[fm][0][q] + bsv[0];
            float gf = acc[fm][1][q] + bsv[1];
            float gg = acc[fm][2][q] + bsv[2];
            float go = acc[fm][3][q] + bsv[3];
            float iv = sigf(gi), fv = sigf(gf);
            float gv = tanh_fast(gg), ov = sigf(go);
            float cn = fv * cv4[fm][q] + iv * gv;
            float hn = ov * tanh_fast(cn);
            cv4[fm][q] = cn;
            const int lanep = (lh * 4 + q) + 16 * ksub;
            htile[(mf * 64 + lanep) * 8 + e] = __builtin_bit_cast(u16, (f16)hn);
        }
    }
    {
        f32x4* cb = (f32x4*)(cws + ((size_t)id * 512 + tid) * 8);
        cb[0] = cv4[0]; cb[1] = cv4[1];
    }

    // ---- epilogue B: cross-wave (wc) reduce of out_{t-1} strip (16 cols) ----
    if (do_out) {
        if (wc == 1) {
            float* P = (float*)(smem + wr * 2048);
            #pragma unroll
            for (int fm = 0; fm < 2; ++fm)
                #pragma unroll
                for (int q = 0; q < 4; ++q)
                    P[(fm * 16 + lh * 4 + q) * 16 + ll] = acc_o[fm][q];
        }
        __syncthreads();
        if (wc == 0) {
            const float* P = (const float*)(smem + wr * 2048);
            const float bo = b_out[jb * 16 + ll];
            #pragma unroll
            for (int fm = 0; fm < 2; ++fm)
                #pragma unroll
                for (int q = 0; q < 4; ++q) {
                    const int rloc = wr * 32 + fm * 16 + lh * 4 + q;
                    float v = acc_o[fm][q] + P[(fm * 16 + lh * 4 + q) * 16 + ll] + bo;
                    __builtin_nontemporal_store(
                        v, out_prev + ((size_t)mb * 128 + rloc) * NV + jb * 16 + ll);
                }
        }
    }

    // ---- epilogue C: convert X[:, t+2] -> fragment-linear fp16 (NT loads) ----
    if (do_xconv && jb < 8) {
        const int r = tid >> 2, kq = tid & 3;   // r 0..127, kq 0..3 (8 cols each)
        const float* xsrc = X + ((size_t)(mb * 128 + r) * T_X + (t + 2)) * NV + jb * 32 + kq * 8;
        f32x4 xv0 = __builtin_nontemporal_load((const f32x4*)xsrc);
        f32x4 xv1 = __builtin_nontemporal_load((const f32x4*)(xsrc + 4));
        f16x8 v;
        #pragma unroll
        for (int j = 0; j < 4; ++j) { v[j] = (f16)xv0[j]; v[4 + j] = (f16)xv1[j]; }
        u16* xt = Xf_n2 + ((size_t)(mb * 8 + jb)) * 4096;
        const int mf = r >> 4;
        const int lanep = (r & 15) + 16 * kq;
        *(f16x8*)(xt + (mf * 64 + lanep) * 8) = v;
    }
}

// ====================== final output projection (t=127 only) ======================
__global__ __launch_bounds__(256)
void out_proj(const u16* __restrict__ Hin, const u16* __restrict__ BO,
              const float* __restrict__ b_out, float* __restrict__ out)
{
    __shared__ char smem[24576];

    const int id  = blockIdx.x;
    const int xcd = id & 7, g2 = id >> 3;
    const int nb  = g2 & 3;
    const int mb  = xcd + 8 * (g2 >> 2);

    const int tid = threadIdx.x, lane = tid & 63, wv = tid >> 6;
    const int wr = wv >> 1, wc = wv & 1;

    f32x4 acc[4][2];
    #pragma unroll
    for (int a = 0; a < 4; ++a) { acc[a][0] = (f32x4){0,0,0,0}; acc[a][1] = (f32x4){0,0,0,0}; }

    auto stage = [&](int kt, int buf) {
        char* base = smem + buf * 12288;
        const char* asrc = (const char*)(Hin + ((size_t)(mb * 16 + kt)) * 4096);
        GLOAD_LDS16(asrc + wv * 2048 + lane * 16,        base + wv * 2048);
        GLOAD_LDS16(asrc + wv * 2048 + 1024 + lane * 16, base + wv * 2048 + 1024);
        const char* bsrc = (const char*)(BO + ((size_t)(kt * 4 + nb)) * 2048);
        GLOAD_LDS16(bsrc + wv * 1024 + lane * 16, base + 8192 + wv * 1024);
    };
    auto compute = [&](int buf) {
        const char* base = smem + buf * 12288;
        f16x8 bfr[2];
        #pragma unroll
        for (int fq = 0; fq < 2; ++fq)
            bfr[fq] = *(const f16x8*)(base + 8192 + (((wc * 2 + fq) * 64 + lane) << 4));
        #pragma unroll
        for (int fm = 0; fm < 4; ++fm) {
            f16x8 af = *(const f16x8*)(base + (((wr * 4 + fm) * 64 + lane) << 4));
            #pragma unroll
            for (int fq = 0; fq < 2; ++fq)
                acc[fm][fq] = __builtin_amdgcn_mfma_f32_16x16x32_f16(af, bfr[fq], acc[fm][fq], 0, 0, 0);
        }
    };

    stage(0, 0);
    __syncthreads();
    for (int kt = 0; kt < 16; ++kt) {
        const int cur = kt & 1;
        if (kt + 1 < 16) stage(kt + 1, cur ^ 1);
        compute(cur);
        __syncthreads();
    }

    const int ll = lane & 15, lh = lane >> 4;
    float bov[2];
    #pragma unroll
    for (int fq = 0; fq < 2; ++fq) bov[fq] = b_out[nb * 64 + (wc * 2 + fq) * 16 + ll];

    #pragma unroll
    for (int fm = 0; fm < 4; ++fm)
        #pragma unroll
        for (int fq = 0; fq < 2; ++fq)
            #pragma unroll
            for (int q = 0; q < 4; ++q) {
                const int row = mb * 128 + wr * 64 + fm * 16 + lh * 4 + q;
                const int col = nb * 64 + (wc * 2 + fq) * 16 + ll;
                __builtin_nontemporal_store(acc[fm][fq][q] + bov[fq],
                                            out + (size_t)row * NV + col);
            }
}

// ============================ host =============================
extern "C" void kernel_launch(void* const* d_in, const int* in_sizes, int n_in,
                              void* d_out, int out_size, void* d_ws, size_t ws_size,
                              hipStream_t stream) {
    const float* X     = (const float*)d_in[0];
    const float* a0    = (const float*)d_in[1];
    const float* c0    = (const float*)d_in[2];
    const float* W_ih  = (const float*)d_in[3];
    const float* W_hh  = (const float*)d_in[4];
    const float* b_ih  = (const float*)d_in[5];
    const float* b_hh  = (const float*)d_in[6];
    const float* W_out = (const float*)d_in[7];
    const float* b_out = (const float*)d_in[8];
    float* out = (float*)d_out;

    char* w = (char*)d_ws;
    u16*   H0   = (u16*)(w);                                   // 4 MB
    u16*   H1   = (u16*)(w + ((size_t)4 << 20));               // 4 MB
    float* cws  = (float*)(w + ((size_t)8 << 20));             // 8 MB
    u16*   BG   = (u16*)(w + ((size_t)16 << 20));              // 3 MB
    u16*   BOs  = (u16*)(w + ((size_t)19 << 20));              // 256 KB
    u16*   BOo  = (u16*)(w + ((size_t)19 << 20) + 262144);     // 256 KB
    float* bsv  = (float*)(w + ((size_t)19 << 20) + 524288);   // 8 KB
    u16*   Xf   = (u16*)(w + ((size_t)20 << 20));              // 3 x 2 MB rotating

    prep<<<8192, 256, 0, stream>>>(X, a0, c0, W_ih, W_hh, b_ih, b_hh, W_out,
                                   H0, cws, BG, BOs, BOo, bsv, Xf);

    for (int t = 0; t < T_X; ++t) {
        const u16* hi = (t & 1) ? H1 : H0;
        u16*       ho = (t & 1) ? H0 : H1;
        const u16* xc = Xf + (size_t)(t % 3) * 1048576;
        u16*       xn = Xf + (size_t)((t + 2) % 3) * 1048576;
        float* outp = out + (size_t)(t > 0 ? t - 1 : 0) * M_DIM * NV;
        step_fused<<<512, 512, 0, stream>>>(X, xc, xn, hi, ho, cws, BG, BOs, bsv, b_out,
                                            outp, t, t > 0 ? 1 : 0, t < T_X - 2 ? 1 : 0);
    }
    // final out for t=127 (h in H0 after odd t=127)
    out_proj<<<128, 256, 0, stream>>>(H0, BOo, b_out, out + (size_t)(T_X - 1) * M_DIM * NV);
}

// Round 9
// 3272.283 us; speedup vs baseline: 1.9027x; 1.0536x over previous
//
#include <hip/hip_runtime.h>
#include <math.h>

typedef _Float16 f16;
typedef _Float16 f16x8 __attribute__((ext_vector_type(8)));
typedef float f32x4 __attribute__((ext_vector_type(4)));
typedef unsigned int u32;
typedef unsigned short u16;

#define M_DIM 4096
#define T_X   128
#define NV    256
#define NA    512
#define NG    2048
#define NKT   24   // gates k-tiles of 32 (8 X-tiles + 16 h-tiles)

__device__ __forceinline__ float sigf(float x) { return 1.0f / (1.0f + __expf(-x)); }
__device__ __forceinline__ float tanh_fast(float x) {
    float t = __expf(2.0f * x);
    return (t - 1.0f) / (t + 1.0f);
}

#define GLOAD_LDS16(G, L) \
    __builtin_amdgcn_global_load_lds((const __attribute__((address_space(1))) u32*)(G), \
                                     (__attribute__((address_space(3))) u32*)(L), 16, 0, 0)

// ============================ prep =============================
// BG : [kt 24][jb 16] tiles 4096 u16 (gates weights, fragment-linear)
// BOs: [kt 16][s 16] strips 512 u16 (fused out-proj weights)
// BOo: [kt 16][nb 4] tiles 2048 u16 (final out_proj kernel)
// H  : [mb 32][kt 16] tiles 4096 u16 fragment-linear h (128 rows x 32 k)
// Xf : 3 rotating buffers of [mb 32][kt 8] tiles 4096 u16; prep fills t=0, t=1
// cws: fragment-contiguous c for 512-thread blocks: [(id*512 + tid)*8 + fm*4 + q]
__global__ void prep(const float* __restrict__ X,
                     const float* __restrict__ a0, const float* __restrict__ c0,
                     const float* __restrict__ W_ih, const float* __restrict__ W_hh,
                     const float* __restrict__ b_ih, const float* __restrict__ b_hh,
                     const float* __restrict__ W_out,
                     u16* __restrict__ H0, float* __restrict__ cws,
                     u16* __restrict__ BG, u16* __restrict__ BOs, u16* __restrict__ BOo,
                     float* __restrict__ bs, u16* __restrict__ Xf)
{
    const int N_BG  = NKT * 16 * 4096;   // 1,572,864
    const int N_BOS = 16 * 16 * 512;     // 131,072
    const int N_BOO = 16 * 4 * 2048;     // 131,072
    const int N_BS  = NG;                // 2,048
    const int N_H   = 32 * 16 * 4096;    // 2,097,152
    const int N_XF  = 2 * 32 * 8 * 4096; // 2,097,152 (timesteps 0 and 1)
    const int N_C   = M_DIM * NA;        // 2,097,152
    const int NT = N_BG + N_BOS + N_BOO + N_BS + N_H + N_XF + N_C;
    for (int idx = blockIdx.x * blockDim.x + threadIdx.x; idx < NT;
         idx += gridDim.x * blockDim.x) {
        int i = idx;
        if (i < N_BG) {
            int tile = i >> 12, w = i & 4095;
            int jb = tile & 15, kt = tile >> 4;
            int f = w >> 9, lane = (w >> 3) & 63, e = w & 7;
            int wcc = f >> 2, g = f & 3;
            int n = g * NA + jb * 32 + wcc * 16 + (lane & 15);
            int k = kt * 32 + ((lane >> 4) << 3) + e;
            float v = (k < NV) ? W_ih[n * NV + k] : W_hh[n * NA + (k - NV)];
            BG[i] = __builtin_bit_cast(u16, (f16)v);
            continue;
        }
        i -= N_BG;
        if (i < N_BOS) {
            int tile = i >> 9, w = i & 511;
            int s = tile & 15, kt = tile >> 4;
            int lane = w >> 3, e = w & 7;
            int n = s * 16 + (lane & 15);
            int k = kt * 32 + ((lane >> 4) << 3) + e;
            BOs[i] = __builtin_bit_cast(u16, (f16)W_out[n * NA + k]);
            continue;
        }
        i -= N_BOS;
        if (i < N_BOO) {
            int tile = i >> 11, w = i & 2047;
            int nb = tile & 3, kt = tile >> 2;
            int f = w >> 9, lane = (w >> 3) & 63, e = w & 7;
            int n = nb * 64 + f * 16 + (lane & 15);
            int k = kt * 32 + ((lane >> 4) << 3) + e;
            BOo[i] = __builtin_bit_cast(u16, (f16)W_out[n * NA + k]);
            continue;
        }
        i -= N_BOO;
        if (i < N_BS) { bs[i] = b_ih[i] + b_hh[i]; continue; }
        i -= N_BS;
        if (i < N_H) {
            int tile = i >> 12, w = i & 4095;
            int kt = tile & 15, mb = tile >> 4;
            int mf = w >> 9, lane = (w >> 3) & 63, e = w & 7;
            int m = mb * 128 + mf * 16 + (lane & 15);
            int k = kt * 32 + ((lane >> 4) << 3) + e;
            H0[i] = __builtin_bit_cast(u16, (f16)a0[m * NA + k]);
            continue;
        }
        i -= N_H;
        if (i < N_XF) {
            int b = i >> 20, j = i & 1048575;
            int tile = j >> 12, w = j & 4095;
            int kt = tile & 7, mb = tile >> 3;
            int mf = w >> 9, lane = (w >> 3) & 63, e = w & 7;
            int m = mb * 128 + mf * 16 + (lane & 15);
            int k = kt * 32 + ((lane >> 4) << 3) + e;
            Xf[i] = __builtin_bit_cast(u16, (f16)X[(size_t)m * (T_X * NV) + b * NV + k]);
            continue;
        }
        i -= N_XF;
        {
            // c init for 512-thread step blocks: i = (id*512 + tid)*8 + fm*4 + q
            int id  = i >> 12;           // block 0..511
            int rem = i & 4095;          // 512 threads x 8
            int tid = rem >> 3, r8 = rem & 7;
            int fm = r8 >> 2, q = r8 & 3;
            int xcd = id & 7, g2 = id >> 3;
            int jb = g2 & 15, mb = xcd + 8 * (g2 >> 4);
            int lane = tid & 63, wv = tid >> 6;     // wv 0..7
            int wr = wv >> 1, wc = wv & 1;          // wr 0..3
            int ll = lane & 15, lh = lane >> 4;
            int m = mb * 128 + (wr * 2 + fm) * 16 + lh * 4 + q;
            int col = jb * 32 + wc * 16 + ll;
            cws[i] = c0[(size_t)m * NA + col];
        }
    }
}

// ====================== fused step kernel (8 waves) ======================
// gates_t + cell update + h_t ; out_{t-1} fused ; X[:, t+2] convert.
// grid 512 (XCD-swizzled), 512 threads = 8 waves (4 wr x 2 wc).
// LDS 64KB: 3 x 16KB staging bufs + 16KB BO strips. 2 blocks/CU = 4 waves/SIMD.
__global__ __launch_bounds__(512, 4)
void step_fused(const float* __restrict__ X,
                const u16* __restrict__ Xf_cur, u16* __restrict__ Xf_n2,
                const u16* __restrict__ Hin, u16* __restrict__ Hout,
                float* __restrict__ cws,
                const u16* __restrict__ BG, const u16* __restrict__ BOs,
                const float* __restrict__ bs, const float* __restrict__ b_out,
                float* __restrict__ out_prev, int t, int do_out, int do_xconv)
{
    __shared__ char smem[65536];
    char* BO_lds = smem + 49152;

    const int id  = blockIdx.x;
    const int xcd = id & 7, g2 = id >> 3;
    const int jb  = g2 & 15;
    const int mb  = xcd + 8 * (g2 >> 4);

    const int tid = threadIdx.x, lane = tid & 63, wv = tid >> 6;  // wv 0..7
    const int wr = wv >> 1, wc = wv & 1;                          // wr 0..3

    f32x4 acc[2][4];
    #pragma unroll
    for (int a = 0; a < 2; ++a)
        #pragma unroll
        for (int b = 0; b < 4; ++b) acc[a][b] = (f32x4){0.f, 0.f, 0.f, 0.f};
    f32x4 acc_o[2];
    acc_o[0] = (f32x4){0.f, 0.f, 0.f, 0.f};
    acc_o[1] = (f32x4){0.f, 0.f, 0.f, 0.f};

    auto stage = [&](int ktn, int buf) {
        char* base = smem + buf * 16384;
        const char* asrc = (ktn < 8)
            ? (const char*)(Xf_cur + ((size_t)(mb * 8 + ktn)) * 4096)
            : (const char*)(Hin + ((size_t)(mb * 16 + (ktn - 8))) * 4096);
        GLOAD_LDS16(asrc + wv * 1024 + lane * 16, base + wv * 1024);
        const char* bsrc = (const char*)(BG + ((size_t)(ktn * 16 + jb)) * 4096);
        GLOAD_LDS16(bsrc + wv * 1024 + lane * 16, base + 8192 + wv * 1024);
    };
    auto compute = [&](int ktn, int buf) {
        const char* base = smem + buf * 16384;
        f16x8 af[2], bfr[4];
        #pragma unroll
        for (int g = 0; g < 4; ++g)
            bfr[g] = *(const f16x8*)(base + 8192 + (((wc * 4 + g) * 64 + lane) << 4));
        #pragma unroll
        for (int fm = 0; fm < 2; ++fm)
            af[fm] = *(const f16x8*)(base + (((wr * 2 + fm) * 64 + lane) << 4));
        __builtin_amdgcn_s_setprio(1);
        #pragma unroll
        for (int fm = 0; fm < 2; ++fm)
            #pragma unroll
            for (int g = 0; g < 4; ++g)
                acc[fm][g] = __builtin_amdgcn_mfma_f32_16x16x32_f16(af[fm], bfr[g], acc[fm][g], 0, 0, 0);
        if (do_out && ktn >= 8 && ((ktn - 8) & 1) == wc) {
            f16x8 bo = *(const f16x8*)(BO_lds + (ktn - 8) * 1024 + lane * 16);
            #pragma unroll
            for (int fm = 0; fm < 2; ++fm)
                acc_o[fm] = __builtin_amdgcn_mfma_f32_16x16x32_f16(af[fm], bo, acc_o[fm], 0, 0, 0);
        }
        __builtin_amdgcn_s_setprio(0);
    };

    // prologue: BO strips (2 loads/wave) + first two pipeline stages (2 loads/wave each)
    #pragma unroll
    for (int i = 0; i < 2; ++i) {
        int kt = wv * 2 + i;
        const char* src = (const char*)(BOs + ((size_t)(kt * 16 + jb)) * 512);
        GLOAD_LDS16(src + lane * 16, BO_lds + kt * 1024);
    }
    stage(0, 0);
    stage(1, 1);

    // main loop: fully unrolled; one barrier + counted vmcnt per tile; loads span barriers
    #pragma unroll
    for (int kt = 0; kt < NKT; ++kt) {
        if (kt < NKT - 1) asm volatile("s_waitcnt vmcnt(2)" ::: "memory");
        else              asm volatile("s_waitcnt vmcnt(0)" ::: "memory");
        __builtin_amdgcn_s_barrier();
        if (kt + 2 < NKT) stage(kt + 2, (kt + 2) % 3);
        compute(kt, kt % 3);
    }

    // ---- epilogue A: bias + activations + cell update + h store ----
    const int ll = lane & 15, lh = lane >> 4;
    const int colg = jb * 32 + wc * 16 + ll;
    float bsv[4];
    #pragma unroll
    for (int g = 0; g < 4; ++g) bsv[g] = bs[g * NA + colg];
    f32x4 cv4[2];
    {
        const f32x4* cb = (const f32x4*)(cws + ((size_t)id * 512 + tid) * 8);
        cv4[0] = __builtin_nontemporal_load(cb);
        cv4[1] = __builtin_nontemporal_load(cb + 1);
    }

    u16* htile = Hout + ((size_t)(mb * 16 + jb)) * 4096;
    const int ksub = wc * 2 + (ll >> 3);
    const int e = ll & 7;

    #pragma unroll
    for (int fm = 0; fm < 2; ++fm) {
        const int mf = wr * 2 + fm;
        #pragma unroll
        for (int q = 0; q < 4; ++q) {
            float gi = acc[fm][0][q] + bsv[0];
            float gf = acc[fm][1][q] + bsv[1];
            float gg = acc[fm][2][q] + bsv[2];
            float go = acc[fm][3][q] + bsv[3];
            float iv = sigf(gi), fv = sigf(gf);
            float gv = tanh_fast(gg), ov = sigf(go);
            float cn = fv * cv4[fm][q] + iv * gv;
            float hn = ov * tanh_fast(cn);
            cv4[fm][q] = cn;
            const int lanep = (lh * 4 + q) + 16 * ksub;
            htile[(mf * 64 + lanep) * 8 + e] = __builtin_bit_cast(u16, (f16)hn);
        }
    }
    {
        f32x4* cb = (f32x4*)(cws + ((size_t)id * 512 + tid) * 8);
        __builtin_nontemporal_store(cv4[0], cb);
        __builtin_nontemporal_store(cv4[1], cb + 1);
    }

    // ---- epilogue B: cross-wave (wc) reduce of out_{t-1} strip (16 cols) ----
    if (do_out) {
        if (wc == 1) {
            float* P = (float*)(smem + wr * 2560);   // stride 20 floats: conflict-free
            #pragma unroll
            for (int fm = 0; fm < 2; ++fm)
                #pragma unroll
                for (int q = 0; q < 4; ++q)
                    P[(fm * 16 + lh * 4 + q) * 20 + ll] = acc_o[fm][q];
        }
        __syncthreads();
        if (wc == 0) {
            const float* P = (const float*)(smem + wr * 2560);
            const float bo = b_out[jb * 16 + ll];
            #pragma unroll
            for (int fm = 0; fm < 2; ++fm)
                #pragma unroll
                for (int q = 0; q < 4; ++q) {
                    const int rloc = wr * 32 + fm * 16 + lh * 4 + q;
                    float v = acc_o[fm][q] + P[(fm * 16 + lh * 4 + q) * 20 + ll] + bo;
                    __builtin_nontemporal_store(
                        v, out_prev + ((size_t)mb * 128 + rloc) * NV + jb * 16 + ll);
                }
        }
    }

    // ---- epilogue C: convert X[:, t+2] -> fragment-linear fp16 (NT loads) ----
    if (do_xconv && jb < 8) {
        const int r = tid >> 2, kq = tid & 3;   // r 0..127, kq 0..3 (8 cols each)
        const float* xsrc = X + ((size_t)(mb * 128 + r) * T_X + (t + 2)) * NV + jb * 32 + kq * 8;
        f32x4 xv0 = __builtin_nontemporal_load((const f32x4*)xsrc);
        f32x4 xv1 = __builtin_nontemporal_load((const f32x4*)(xsrc + 4));
        f16x8 v;
        #pragma unroll
        for (int j = 0; j < 4; ++j) { v[j] = (f16)xv0[j]; v[4 + j] = (f16)xv1[j]; }
        u16* xt = Xf_n2 + ((size_t)(mb * 8 + jb)) * 4096;
        const int mf = r >> 4;
        const int lanep = (r & 15) + 16 * kq;
        *(f16x8*)(xt + (mf * 64 + lanep) * 8) = v;
    }
}

// ====================== final output projection (t=127 only) ======================
__global__ __launch_bounds__(256)
void out_proj(const u16* __restrict__ Hin, const u16* __restrict__ BO,
              const float* __restrict__ b_out, float* __restrict__ out)
{
    __shared__ char smem[24576];

    const int id  = blockIdx.x;
    const int xcd = id & 7, g2 = id >> 3;
    const int nb  = g2 & 3;
    const int mb  = xcd + 8 * (g2 >> 2);

    const int tid = threadIdx.x, lane = tid & 63, wv = tid >> 6;
    const int wr = wv >> 1, wc = wv & 1;

    f32x4 acc[4][2];
    #pragma unroll
    for (int a = 0; a < 4; ++a) { acc[a][0] = (f32x4){0,0,0,0}; acc[a][1] = (f32x4){0,0,0,0}; }

    auto stage = [&](int kt, int buf) {
        char* base = smem + buf * 12288;
        const char* asrc = (const char*)(Hin + ((size_t)(mb * 16 + kt)) * 4096);
        GLOAD_LDS16(asrc + wv * 2048 + lane * 16,        base + wv * 2048);
        GLOAD_LDS16(asrc + wv * 2048 + 1024 + lane * 16, base + wv * 2048 + 1024);
        const char* bsrc = (const char*)(BO + ((size_t)(kt * 4 + nb)) * 2048);
        GLOAD_LDS16(bsrc + wv * 1024 + lane * 16, base + 8192 + wv * 1024);
    };
    auto compute = [&](int buf) {
        const char* base = smem + buf * 12288;
        f16x8 bfr[2];
        #pragma unroll
        for (int fq = 0; fq < 2; ++fq)
            bfr[fq] = *(const f16x8*)(base + 8192 + (((wc * 2 + fq) * 64 + lane) << 4));
        #pragma unroll
        for (int fm = 0; fm < 4; ++fm) {
            f16x8 af = *(const f16x8*)(base + (((wr * 4 + fm) * 64 + lane) << 4));
            #pragma unroll
            for (int fq = 0; fq < 2; ++fq)
                acc[fm][fq] = __builtin_amdgcn_mfma_f32_16x16x32_f16(af, bfr[fq], acc[fm][fq], 0, 0, 0);
        }
    };

    stage(0, 0);
    __syncthreads();
    for (int kt = 0; kt < 16; ++kt) {
        const int cur = kt & 1;
        if (kt + 1 < 16) stage(kt + 1, cur ^ 1);
        compute(cur);
        __syncthreads();
    }

    const int ll = lane & 15, lh = lane >> 4;
    float bov[2];
    #pragma unroll
    for (int fq = 0; fq < 2; ++fq) bov[fq] = b_out[nb * 64 + (wc * 2 + fq) * 16 + ll];

    #pragma unroll
    for (int fm = 0; fm < 4; ++fm)
        #pragma unroll
        for (int fq = 0; fq < 2; ++fq)
            #pragma unroll
            for (int q = 0; q < 4; ++q) {
                const int row = mb * 128 + wr * 64 + fm * 16 + lh * 4 + q;
                const int col = nb * 64 + (wc * 2 + fq) * 16 + ll;
                __builtin_nontemporal_store(acc[fm][fq][q] + bov[fq],
                                            out + (size_t)row * NV + col);
            }
}

// ============================ host =============================
extern "C" void kernel_launch(void* const* d_in, const int* in_sizes, int n_in,
                              void* d_out, int out_size, void* d_ws, size_t ws_size,
                              hipStream_t stream) {
    const float* X     = (const float*)d_in[0];
    const float* a0    = (const float*)d_in[1];
    const float* c0    = (const float*)d_in[2];
    const float* W_ih  = (const float*)d_in[3];
    const float* W_hh  = (const float*)d_in[4];
    const float* b_ih  = (const float*)d_in[5];
    const float* b_hh  = (const float*)d_in[6];
    const float* W_out = (const float*)d_in[7];
    const float* b_out = (const float*)d_in[8];
    float* out = (float*)d_out;

    char* w = (char*)d_ws;
    u16*   H0   = (u16*)(w);                                   // 4 MB
    u16*   H1   = (u16*)(w + ((size_t)4 << 20));               // 4 MB
    float* cws  = (float*)(w + ((size_t)8 << 20));             // 8 MB
    u16*   BG   = (u16*)(w + ((size_t)16 << 20));              // 3 MB
    u16*   BOs  = (u16*)(w + ((size_t)19 << 20));              // 256 KB
    u16*   BOo  = (u16*)(w + ((size_t)19 << 20) + 262144);     // 256 KB
    float* bsv  = (float*)(w + ((size_t)19 << 20) + 524288);   // 8 KB
    u16*   Xf   = (u16*)(w + ((size_t)20 << 20));              // 3 x 2 MB rotating

    prep<<<8192, 256, 0, stream>>>(X, a0, c0, W_ih, W_hh, b_ih, b_hh, W_out,
                                   H0, cws, BG, BOs, BOo, bsv, Xf);

    for (int t = 0; t < T_X; ++t) {
        const u16* hi = (t & 1) ? H1 : H0;
        u16*       ho = (t & 1) ? H0 : H1;
        const u16* xc = Xf + (size_t)(t % 3) * 1048576;
        u16*       xn = Xf + (size_t)((t + 2) % 3) * 1048576;
        float* outp = out + (size_t)(t > 0 ? t - 1 : 0) * M_DIM * NV;
        step_fused<<<512, 512, 0, stream>>>(X, xc, xn, hi, ho, cws, BG, BOs, bsv, b_out,
                                            outp, t, t > 0 ? 1 : 0, t < T_X - 2 ? 1 : 0);
    }
    // final out for t=127 (h in H0 after odd t=127)
    out_proj<<<128, 256, 0, stream>>>(H0, BOo, b_out, out + (size_t)(T_X - 1) * M_DIM * NV);
}